// Round 13
// baseline (359.426 us; speedup 1.0000x reference)
//
#include <hip/hip_runtime.h>
#include <math.h>

// Preisach hysteresis, TWO kernels, no cross-block dependencies inside either.
// Measured ledger: 1-block build ~60us (r5/6/11); per-CU redundant build
// ~50-60us (r8); grid.sync ~170us (r10); flag-spin ~100-400us (r12);
// best = r9's 3-node pipeline at 24.9us (~10us work + node overhead).
// This round removes the row->col build dependency algebraically:
//  K1 build_cols_direct: one wave per column b computes C[.][b] DIRECTLY
//     from raw (strided-j partial sums, 4KB LDS bounce, then the validated
//     single 6-step shfl-chain scan over j). 51 blocks, fully parallel.
//  K2 hyst_main: round-9/12-validated wave-per-t backward-record scan with
//     LOCAL chunk stats (r12-validated path) and deferred per-lane lookups.
//
// Table: C[a][b] = sum_{alpha_idx<a, beta_idx<b, beta<=alpha} softplus(raw),
// a,b in [0,L], row-major stride SP=202. packed p(i,j)=L*i-i(i-1)/2+(j-i).
// Single-chain scans assume L+1 <= 256 (here L=200).

__device__ __forceinline__ float softplus_f(float x) {
    return fmaxf(x, 0.0f) + log1pf(expf(-fabsf(x)));
}

__global__ __launch_bounds__(256) void build_cols_direct(
    const float* __restrict__ raw,
    float* __restrict__ Cg,      // W*SP floats
    int L)
{
    __shared__ float Sbuf[4][256];   // per-wave S_j bounce buffer
    const int W  = L + 1;
    const int SP = (W + 1) & ~1;
    const int lane = threadIdx.x & 63;
    const int wid  = threadIdx.x >> 6;
    const int b = blockIdx.x * 4 + wid;      // column index
    const bool active = (b < W);

    // ---- phase A: strided j (load-balanced); serial sum over i ----
    if (active) {
#pragma unroll
        for (int k = 0; k < 4; ++k) {
            const int j = lane + 64 * k;
            if (j < L) {
                const int cap = min(j + 1, b);   // i in [0, cap)
                float s = 0.0f;
                int p = j;                        // p(0,j)
                for (int i = 0; i < cap; ++i) {
                    s += softplus_f(raw[p]);
                    p += (L - 1) - i;             // p(i+1,j)-p(i,j)
                }
                Sbuf[wid][j] = s;
            }
        }
    }
    __syncthreads();   // all 4 waves present (no early return)

    // ---- phase B: contiguous scan over j (validated single shfl chain) ----
    if (active) {
        float s4[4];
        float run = 0.0f;
#pragma unroll
        for (int q = 0; q < 4; ++q) {
            const int j = 4 * lane + q;
            const float d = (j < L) ? Sbuf[wid][j] : 0.0f;
            run += d; s4[q] = run;               // lane-local inclusive
        }
        float x = run;
        for (int o = 1; o < 64; o <<= 1) {
            const float tv = __shfl_up(x, o);
            if (lane >= o) x += tv;
        }
        const float excl = x - run;
#pragma unroll
        for (int q = 0; q < 4; ++q) {
            const int j = 4 * lane + q;
            if (j < L) Cg[(size_t)(j + 1) * SP + b] = excl + s4[q];
        }
        if (lane == 0) Cg[b] = 0.0f;             // row a=0
    }
}

__global__ __launch_bounds__(256) void hyst_main(
    const float* __restrict__ h,
    const float* __restrict__ mesh,
    const float* __restrict__ Cg,
    const float* __restrict__ scale,
    const float* __restrict__ offset,
    float* __restrict__ out,
    int T, int L, int n)
{
    extern __shared__ float sm[];
    const int W  = L + 1;
    const int SP = (W + 1) & ~1;
    const int nc = (T + 63) >> 6;

    float* lh  = sm;          // T floats
    float* us  = sm + T;      // nc
    float* dsm = us + nc;     // nc

    const int tid  = threadIdx.x;
    const int lane = tid & 63;
    const int wid  = tid >> 6;
    const int nwv  = blockDim.x >> 6;   // 4

    const int t = blockIdx.x * nwv + wid;

    // stage h[0..tmax] into LDS
    const int tmax = min(T - 1, (int)(blockIdx.x + 1) * nwv - 1);
    const int nh4  = (tmax + 4) >> 2;
    const float4* h4 = (const float4*)h;
    float4* lh4 = (float4*)lh;
    for (int k = tid; k < nh4; k += blockDim.x) lh4[k] = h4[k];

    // xs levels: lane holds levels lane, +64, +128, +192
    float xsr[4];
#pragma unroll
    for (int k = 0; k < 4; ++k) {
        const int jj = lane + 64 * k;
        xsr[k] = (jj < L) ? mesh[2 * jj + 1] : 2.0f;  // 2.0 never matches
    }
    __syncthreads();

    // local per-chunk stats from staged h (r12-validated path)
    const int ncf = tmax >> 6;
    for (int c = wid; c < ncf; c += nwv) {
        const int i = (c << 6) + lane;
        const float hv = lh[i];
        const float hp = (i > 0) ? lh[i - 1] : 0.0f;
        float mu = (hv > hp) ? hv : -1.0f;
        float md = (hv < hp) ? hv : 2.0f;
        for (int o = 1; o < 64; o <<= 1) {
            mu = fmaxf(mu, __shfl_xor(mu, o));
            md = fminf(md, __shfl_xor(md, o));
        }
        if (lane == 0) { us[c] = mu; dsm[c] = md; }
    }
    __syncthreads();

    if (t >= T) return;

    float u_max = -1.0f, d_min = 2.0f;
    int Acov = 0, Bcov = L;
    int nrec = 0;                 // wave-uniform
    int r_up = 0, r_lo = 0, r_Ap = 0, r_Bp = 0;   // per-lane record slot
    float acc = 0.0f;             // per-lane deferred contributions

    auto flushrec = [&]() {
        if (lane < nrec) {
            float contrib;
            if (r_up) {
                contrib = Cg[r_lo * SP + r_Bp] - Cg[r_Ap * SP + r_Bp];
            } else {
                contrib = -((Cg[L * SP + r_Bp] - Cg[L * SP + r_lo])
                          - (Cg[r_Ap * SP + r_Bp] - Cg[r_Ap * SP + r_lo]));
            }
            acc += contrib;
        }
        nrec = 0;
    };
    auto count_le = [&](float v) -> int {
        return __popcll(__ballot(xsr[0] <= v)) + __popcll(__ballot(xsr[1] <= v))
             + __popcll(__ballot(xsr[2] <= v)) + __popcll(__ballot(xsr[3] <= v));
    };
    auto count_lt = [&](float v) -> int {
        return __popcll(__ballot(xsr[0] < v)) + __popcll(__ballot(xsr[1] < v))
             + __popcll(__ballot(xsr[2] < v)) + __popcll(__ballot(xsr[3] < v));
    };
    auto process_chunk = [&](int c) {
        const int i = (c << 6) + lane;      // i <= ct*64+63 <= tmax
        const float hv = lh[i];
        const float hp = (i > 0) ? lh[i - 1] : 0.0f;
        const bool valid = (i <= t);
        const bool isup = valid && (hv > hp);
        const bool isdn = valid && (hv < hp);
        unsigned long long mup = __ballot(isup && hv > u_max);
        unsigned long long mdn = __ballot(isdn && hv < d_min);
        unsigned long long m = mup | mdn;
        while (m) {
            const int rl = 63 - __builtin_clzll(m);   // largest i first
            const float v = __shfl(hv, rl);
            if ((mup >> rl) & 1ull) {
                u_max = v;
                const int lo = count_le(v);
                if (lo > Acov) {
                    if (lane == nrec) { r_up = 1; r_lo = lo; r_Ap = Acov; r_Bp = Bcov; }
                    ++nrec;
                    Acov = lo;
                    if (nrec == 64) flushrec();
                }
            } else {
                d_min = v;
                const int lo = count_lt(v);
                if (lo < Bcov) {
                    if (lane == nrec) { r_up = 0; r_lo = lo; r_Ap = Acov; r_Bp = Bcov; }
                    ++nrec;
                    Bcov = lo;
                    if (nrec == 64) flushrec();
                }
            }
            const unsigned long long below =
                (rl == 0) ? 0ull : ((1ull << rl) - 1ull);
            mup = __ballot(isup && hv > u_max) & below;
            mdn = __ballot(isdn && hv < d_min) & below;
            m = mup | mdn;
        }
    };

    const int ct = t >> 6;
    process_chunk(ct);  // partial top chunk (valid mask), exact

    for (int g = (ct - 1) >> 6; g >= 0; --g) {   // ct==0 -> skipped
        if (Acov >= L || Bcov <= 0) break;
        const int cbase = g << 6;
        const int c = cbase + lane;
        const bool act = (c < ct);
        const float vu = act ? us[c] : -1.0f;
        const float vd = act ? dsm[c] : 2.0f;
        // suffix scans (higher lanes = later chunks in backward order)
        float su = vu, sd = vd;
        for (int o = 1; o < 64; o <<= 1) {
            su = fmaxf(su, __shfl_down(su, o));
            sd = fminf(sd, __shfl_down(sd, o));
        }
        float sue = __shfl_down(su, 1);
        float sde = __shfl_down(sd, 1);
        if (lane == 63) { sue = -1.0f; sde = 2.0f; }
        const bool enter = act && ((vu > fmaxf(u_max, sue)) ||
                                   (vd < fminf(d_min, sde)));
        unsigned long long em = __ballot(enter);
        while (em) {
            const int rl = 63 - __builtin_clzll(em);
            process_chunk(cbase + rl);
            em &= ~(1ull << rl);
            if (Acov >= L || Bcov <= 0) break;
        }
    }

    flushrec();
    // leftover region keeps initial -1
    if (lane == 0) acc -= Cg[L * SP + Bcov] - Cg[Acov * SP + Bcov];
    for (int o = 1; o < 64; o <<= 1) acc += __shfl_xor(acc, o);
    if (lane == 0) out[t] = scale[0] * (acc / (float)n) + offset[0];
}

extern "C" void kernel_launch(void* const* d_in, const int* in_sizes, int n_in,
                              void* d_out, int out_size, void* d_ws, size_t ws_size,
                              hipStream_t stream) {
    const float* h      = (const float*)d_in[0];
    const float* mesh   = (const float*)d_in[1];
    const float* raw    = (const float*)d_in[2];
    const float* scale  = (const float*)d_in[3];
    const float* offset = (const float*)d_in[4];
    float* out = (float*)d_out;

    const int T = in_sizes[0];
    const int n = in_sizes[2];
    const int L = (int)((sqrt(8.0 * (double)n + 1.0) - 1.0) / 2.0 + 0.5);
    const int W = L + 1;
    const int nc = (T + 63) / 64;

    float* Cg = (float*)d_ws;                 // W*SP floats

    // K1: direct per-column table build (one wave per column, no deps)
    const int ncolblk = (W + 3) / 4;          // 51 blocks
    hipLaunchKernelGGL(build_cols_direct, dim3(ncolblk), dim3(256), 0, stream,
                       raw, Cg, L);

    // K2: main, wave per t, h staged + local chunk stats
    const int nwv = 4;                         // 256 threads = 4 waves
    const int grid = (T + nwv - 1) / nwv;      // 1024 blocks
    const size_t shmem = (size_t)(T + 2 * nc) * sizeof(float);  // ~16.9 KB
    hipLaunchKernelGGL(hyst_main, dim3(grid), dim3(256), shmem, stream,
                       h, mesh, Cg, scale, offset, out, T, L, n);
}

// Round 14
// 63.980 us; speedup vs baseline: 5.6177x; 5.6177x over previous
//
#include <hip/hip_runtime.h>
#include <math.h>

// Preisach hysteresis, TWO kernels, zero cross-block dependencies.
// Ledger (measured): 1-block build ~60us (r5/6/11); redundant per-CU build
// ~55us (r8); grid.sync ~170us (r10); flag-spin ~400us (r12); per-lane
// SERIAL-i direct build ~375us (r13, uncoalesced+latency-bound). Fix: direct
// per-column build with i as the WAVE-serial axis and j as the LANE axis --
// for fixed i, p(i,j) is contiguous in j => coalesced loads; 8 waves split
// i by residue mod 8; LDS combine; validated 6-step shfl-chain scan over j.
// One block per column (grid=201): ~1.8k cy VALU per wave, <1us wall.
//
// Table stored TRANSPOSED: CT[b][a] = C[a][b] = sum_{alpha_idx<a,
// beta_idx<b, beta<=alpha} softplus(raw), row stride SPa=202 -> per-column
// scan writes are coalesced, up-record lookups hit a single CT row.
// packed p(i,j) = L*i - i*(i-1)/2 + (j-i) = rowbase(i) + j,
// rowbase(i) = L*i - i*(i-1)/2 - i.

__device__ __forceinline__ float softplus_f(float x) {
    return fmaxf(x, 0.0f) + log1pf(expf(-fabsf(x)));
}

__global__ __launch_bounds__(512) void build_table_direct(
    const float* __restrict__ raw,
    float* __restrict__ CT,      // W rows (b) x SPa cols (a)
    int L)
{
    __shared__ float Sbuf[8][256];
    const int W   = L + 1;
    const int SPa = (W + 1) & ~1;       // 202
    const int lane = threadIdx.x & 63;
    const int q    = threadIdx.x >> 6;  // wave id = i-residue (0..7)
    const int b    = blockIdx.x;        // column (beta-count index), < W

    // ---- accumulate S_j(b) partials: i wave-serial (i%8==q, i<b), j=lanes ----
    float acc[4] = {0.f, 0.f, 0.f, 0.f};
    for (int i = q; i < b; i += 8) {
        const int rowbase = L * i - (i * (i - 1)) / 2 - i;
#pragma unroll
        for (int k = 0; k < 4; ++k) {
            if (64 * k + 63 >= i) {              // wave-uniform k skip
                const int j = lane + 64 * k;
                float v = 0.0f;
                if (j < L && j >= i) v = softplus_f(raw[rowbase + j]);
                acc[k] += v;
            }
        }
    }
#pragma unroll
    for (int k = 0; k < 4; ++k) {
        const int j = lane + 64 * k;
        if (j < 256) Sbuf[q][j] = acc[k];
    }
    __syncthreads();

    // ---- wave 0: combine 8 partials, scan over j, write CT row b ----
    if (q == 0) {
        float s4[4];
        float run = 0.0f;
#pragma unroll
        for (int qq = 0; qq < 4; ++qq) {
            const int j = 4 * lane + qq;
            float d = 0.0f;
            if (j < L) {
#pragma unroll
                for (int p = 0; p < 8; ++p) d += Sbuf[p][j];
            }
            run += d; s4[qq] = run;              // lane-local inclusive
        }
        float x = run;
        for (int o = 1; o < 64; o <<= 1) {
            const float tv = __shfl_up(x, o);
            if (lane >= o) x += tv;
        }
        const float excl = x - run;
        float* row = CT + (size_t)b * SPa;       // CT[b][a], a = j+1
#pragma unroll
        for (int qq = 0; qq < 4; ++qq) {
            const int j = 4 * lane + qq;
            if (j < L) row[j + 1] = excl + s4[qq];
        }
        if (lane == 0) row[0] = 0.0f;            // a = 0
    }
}

__global__ __launch_bounds__(256) void hyst_main(
    const float* __restrict__ h,
    const float* __restrict__ mesh,
    const float* __restrict__ CT,
    const float* __restrict__ scale,
    const float* __restrict__ offset,
    float* __restrict__ out,
    int T, int L, int n)
{
    extern __shared__ float sm[];
    const int W   = L + 1;
    const int SPa = (W + 1) & ~1;
    const int nc  = (T + 63) >> 6;

    float* lh  = sm;          // T floats
    float* us  = sm + T;      // nc
    float* dsm = us + nc;     // nc

    const int tid  = threadIdx.x;
    const int lane = tid & 63;
    const int wid  = tid >> 6;
    const int nwv  = blockDim.x >> 6;   // 4

    const int t = blockIdx.x * nwv + wid;

    // stage h[0..tmax] into LDS
    const int tmax = min(T - 1, (int)(blockIdx.x + 1) * nwv - 1);
    const int nh4  = (tmax + 4) >> 2;
    const float4* h4 = (const float4*)h;
    float4* lh4 = (float4*)lh;
    for (int k = tid; k < nh4; k += blockDim.x) lh4[k] = h4[k];

    // xs levels: lane holds levels lane, +64, +128, +192
    float xsr[4];
#pragma unroll
    for (int k = 0; k < 4; ++k) {
        const int jj = lane + 64 * k;
        xsr[k] = (jj < L) ? mesh[2 * jj + 1] : 2.0f;  // 2.0 never matches
    }
    __syncthreads();

    // local per-chunk stats from staged h (r12/r13-validated path)
    const int ncf = tmax >> 6;
    for (int c = wid; c < ncf; c += nwv) {
        const int i = (c << 6) + lane;
        const float hv = lh[i];
        const float hp = (i > 0) ? lh[i - 1] : 0.0f;
        float mu = (hv > hp) ? hv : -1.0f;
        float md = (hv < hp) ? hv : 2.0f;
        for (int o = 1; o < 64; o <<= 1) {
            mu = fmaxf(mu, __shfl_xor(mu, o));
            md = fminf(md, __shfl_xor(md, o));
        }
        if (lane == 0) { us[c] = mu; dsm[c] = md; }
    }
    __syncthreads();

    if (t >= T) return;

    float u_max = -1.0f, d_min = 2.0f;
    int Acov = 0, Bcov = L;
    int nrec = 0;                 // wave-uniform
    int r_up = 0, r_lo = 0, r_Ap = 0, r_Bp = 0;   // per-lane record slot
    float acc = 0.0f;             // per-lane deferred contributions

    auto flushrec = [&]() {
        if (lane < nrec) {
            float contrib;
            if (r_up) {
                // C[lo][Bp] - C[Ap][Bp]  (lo,Ap are a-indices; Bp is b)
                contrib = CT[r_Bp * SPa + r_lo] - CT[r_Bp * SPa + r_Ap];
            } else {
                // -((C[L][Bp]-C[L][lo]) - (C[Ap][Bp]-C[Ap][lo]))
                contrib = -((CT[r_Bp * SPa + L] - CT[r_lo * SPa + L])
                          - (CT[r_Bp * SPa + r_Ap] - CT[r_lo * SPa + r_Ap]));
            }
            acc += contrib;
        }
        nrec = 0;
    };
    auto count_le = [&](float v) -> int {
        return __popcll(__ballot(xsr[0] <= v)) + __popcll(__ballot(xsr[1] <= v))
             + __popcll(__ballot(xsr[2] <= v)) + __popcll(__ballot(xsr[3] <= v));
    };
    auto count_lt = [&](float v) -> int {
        return __popcll(__ballot(xsr[0] < v)) + __popcll(__ballot(xsr[1] < v))
             + __popcll(__ballot(xsr[2] < v)) + __popcll(__ballot(xsr[3] < v));
    };
    auto process_chunk = [&](int c) {
        const int i = (c << 6) + lane;      // i <= ct*64+63 <= tmax
        const float hv = lh[i];
        const float hp = (i > 0) ? lh[i - 1] : 0.0f;
        const bool valid = (i <= t);
        const bool isup = valid && (hv > hp);
        const bool isdn = valid && (hv < hp);
        unsigned long long mup = __ballot(isup && hv > u_max);
        unsigned long long mdn = __ballot(isdn && hv < d_min);
        unsigned long long m = mup | mdn;
        while (m) {
            const int rl = 63 - __builtin_clzll(m);   // largest i first
            const float v = __shfl(hv, rl);
            if ((mup >> rl) & 1ull) {
                u_max = v;
                const int lo = count_le(v);
                if (lo > Acov) {
                    if (lane == nrec) { r_up = 1; r_lo = lo; r_Ap = Acov; r_Bp = Bcov; }
                    ++nrec;
                    Acov = lo;
                    if (nrec == 64) flushrec();
                }
            } else {
                d_min = v;
                const int lo = count_lt(v);
                if (lo < Bcov) {
                    if (lane == nrec) { r_up = 0; r_lo = lo; r_Ap = Acov; r_Bp = Bcov; }
                    ++nrec;
                    Bcov = lo;
                    if (nrec == 64) flushrec();
                }
            }
            const unsigned long long below =
                (rl == 0) ? 0ull : ((1ull << rl) - 1ull);
            mup = __ballot(isup && hv > u_max) & below;
            mdn = __ballot(isdn && hv < d_min) & below;
            m = mup | mdn;
        }
    };

    const int ct = t >> 6;
    process_chunk(ct);  // partial top chunk (valid mask), exact

    for (int g = (ct - 1) >> 6; g >= 0; --g) {   // ct==0 -> skipped
        if (Acov >= L || Bcov <= 0) break;
        const int cbase = g << 6;
        const int c = cbase + lane;
        const bool act = (c < ct);
        const float vu = act ? us[c] : -1.0f;
        const float vd = act ? dsm[c] : 2.0f;
        // suffix scans (higher lanes = later chunks in backward order)
        float su = vu, sd = vd;
        for (int o = 1; o < 64; o <<= 1) {
            su = fmaxf(su, __shfl_down(su, o));
            sd = fminf(sd, __shfl_down(sd, o));
        }
        float sue = __shfl_down(su, 1);
        float sde = __shfl_down(sd, 1);
        if (lane == 63) { sue = -1.0f; sde = 2.0f; }
        const bool enter = act && ((vu > fmaxf(u_max, sue)) ||
                                   (vd < fminf(d_min, sde)));
        unsigned long long em = __ballot(enter);
        while (em) {
            const int rl = 63 - __builtin_clzll(em);
            process_chunk(cbase + rl);
            em &= ~(1ull << rl);
            if (Acov >= L || Bcov <= 0) break;
        }
    }

    flushrec();
    // leftover region keeps initial -1:  C[L][Bcov] - C[Acov][Bcov]
    if (lane == 0) acc -= CT[Bcov * SPa + L] - CT[Bcov * SPa + Acov];
    for (int o = 1; o < 64; o <<= 1) acc += __shfl_xor(acc, o);
    if (lane == 0) out[t] = scale[0] * (acc / (float)n) + offset[0];
}

extern "C" void kernel_launch(void* const* d_in, const int* in_sizes, int n_in,
                              void* d_out, int out_size, void* d_ws, size_t ws_size,
                              hipStream_t stream) {
    const float* h      = (const float*)d_in[0];
    const float* mesh   = (const float*)d_in[1];
    const float* raw    = (const float*)d_in[2];
    const float* scale  = (const float*)d_in[3];
    const float* offset = (const float*)d_in[4];
    float* out = (float*)d_out;

    const int T = in_sizes[0];
    const int n = in_sizes[2];
    const int L = (int)((sqrt(8.0 * (double)n + 1.0) - 1.0) / 2.0 + 0.5);
    const int W = L + 1;
    const int nc = (T + 63) / 64;

    float* CT = (float*)d_ws;                 // W*SPa floats (transposed)

    // K1: direct per-column build -- one block per column, i wave-serial,
    // j lane-parallel (coalesced), 8-way i-residue split, LDS combine.
    hipLaunchKernelGGL(build_table_direct, dim3(W), dim3(512), 0, stream,
                       raw, CT, L);

    // K2: main, wave per t, h staged + local chunk stats (r13-validated)
    const int nwv = 4;                         // 256 threads = 4 waves
    const int grid = (T + nwv - 1) / nwv;      // 1024 blocks
    const size_t shmem = (size_t)(T + 2 * nc) * sizeof(float);  // ~16.9 KB
    hipLaunchKernelGGL(hyst_main, dim3(grid), dim3(256), shmem, stream,
                       h, mesh, CT, scale, offset, out, T, L, n);
}

// Round 15
// 44.798 us; speedup vs baseline: 8.0232x; 1.4282x over previous
//
#include <hip/hip_runtime.h>
#include <math.h>

// Preisach hysteresis, TWO kernels, zero cross-block dependencies.
// Ledger (measured): 1-block build ~60us (r5/6/11); redundant per-CU build
// ~55us (r8); grid.sync ~170us (r10); flag-spin ~400us (r12); per-lane
// serial-i build ~375us (r13); r14 direct build 53us -- VALUBusy 25%,
// ~75% stall: branch-wrapped GLOBAL loads + softplus serialized ~100
// latency round-trips per wave. Fix: stage softplus(raw-prefix) into LDS
// (coalesced float4, independent evals = throughput-bound), then the
// i-residue sum loop reads LDS with cndmask predication (no branches, no
// vmcnt stalls). Everything else byte-identical to r14 (absmax 0.0).
//
// Table stored TRANSPOSED: CT[b][a] = C[a][b] = sum_{alpha_idx<a,
// beta_idx<b, beta<=alpha} softplus(raw), row stride SPa=202.
// packed p(i,j) = L*i - i*(i-1)/2 + (j-i) = rowbase(i) + j,
// rowbase(i) = L*i - i*(i-1)/2 - i.  Rows i<b occupy the contiguous
// prefix raw[0 .. nstage(b)), nstage(b) = L*b - b*(b-1)/2.

__device__ __forceinline__ float softplus_f(float x) {
    return fmaxf(x, 0.0f) + log1pf(expf(-fabsf(x)));
}

__global__ __launch_bounds__(512) void build_table_direct(
    const float* __restrict__ raw,
    float* __restrict__ CT,      // W rows (b) x SPa cols (a)
    int L, int n)
{
    extern __shared__ float smem[];
    float* sp   = smem;              // n + pad floats: softplus(raw[.])
    float* Sbuf = smem + n + 256;    // 8*256 floats

    const int W   = L + 1;
    const int SPa = (W + 1) & ~1;       // 202
    const int tid  = threadIdx.x;
    const int lane = tid & 63;
    const int q    = tid >> 6;          // wave id = i-residue (0..7)
    const int b    = blockIdx.x;        // column (beta-count index), < W

    // ---- stage: softplus(raw[0..nstage)) into LDS, coalesced float4 ----
    const int nstage = L * b - (b * (b - 1)) / 2;   // rows i < b
    {
        const int n4 = nstage >> 2;
        const float4* r4 = (const float4*)raw;
        for (int k = tid; k < n4; k += 512) {
            const float4 v = r4[k];
            float4 o;
            o.x = softplus_f(v.x); o.y = softplus_f(v.y);
            o.z = softplus_f(v.z); o.w = softplus_f(v.w);
            *(float4*)&sp[4 * k] = o;
        }
        for (int k = 4 * n4 + tid; k < nstage; k += 512)
            sp[k] = softplus_f(raw[k]);
        // zero the +256 pad (masked lanes may read it)
        for (int k = nstage + tid; k < nstage + 256; k += 512)
            sp[k] = 0.0f;
    }
    __syncthreads();

    // ---- accumulate S_j(b) partials: i wave-serial (i%8==q, i<b),
    //      j lane-parallel from LDS, fully predicated (no branches) ----
    float acc[4] = {0.f, 0.f, 0.f, 0.f};
    for (int i = q; i < b; i += 8) {
        const int rowbase = L * i - (i * (i - 1)) / 2 - i;
#pragma unroll
        for (int k = 0; k < 4; ++k) {
            const int j = lane + 64 * k;
            const float v = sp[rowbase + j];             // in-bounds (padded)
            acc[k] += (j < L && j >= i) ? v : 0.0f;      // cndmask
        }
    }
#pragma unroll
    for (int k = 0; k < 4; ++k) Sbuf[q * 256 + lane + 64 * k] = acc[k];
    __syncthreads();

    // ---- wave 0: combine 8 partials, scan over j, write CT row b ----
    if (q == 0) {
        float s4[4];
        float run = 0.0f;
#pragma unroll
        for (int qq = 0; qq < 4; ++qq) {
            const int j = 4 * lane + qq;
            float d = 0.0f;
            if (j < L) {
#pragma unroll
                for (int p = 0; p < 8; ++p) d += Sbuf[p * 256 + j];
            }
            run += d; s4[qq] = run;              // lane-local inclusive
        }
        float x = run;
        for (int o = 1; o < 64; o <<= 1) {
            const float tv = __shfl_up(x, o);
            if (lane >= o) x += tv;
        }
        const float excl = x - run;
        float* row = CT + (size_t)b * SPa;       // CT[b][a], a = j+1
#pragma unroll
        for (int qq = 0; qq < 4; ++qq) {
            const int j = 4 * lane + qq;
            if (j < L) row[j + 1] = excl + s4[qq];
        }
        if (lane == 0) row[0] = 0.0f;            // a = 0
    }
}

__global__ __launch_bounds__(256) void hyst_main(
    const float* __restrict__ h,
    const float* __restrict__ mesh,
    const float* __restrict__ CT,
    const float* __restrict__ scale,
    const float* __restrict__ offset,
    float* __restrict__ out,
    int T, int L, int n)
{
    extern __shared__ float sm[];
    const int W   = L + 1;
    const int SPa = (W + 1) & ~1;
    const int nc  = (T + 63) >> 6;

    float* lh  = sm;          // T floats
    float* us  = sm + T;      // nc
    float* dsm = us + nc;     // nc

    const int tid  = threadIdx.x;
    const int lane = tid & 63;
    const int wid  = tid >> 6;
    const int nwv  = blockDim.x >> 6;   // 4

    const int t = blockIdx.x * nwv + wid;

    // stage h[0..tmax] into LDS
    const int tmax = min(T - 1, (int)(blockIdx.x + 1) * nwv - 1);
    const int nh4  = (tmax + 4) >> 2;
    const float4* h4 = (const float4*)h;
    float4* lh4 = (float4*)lh;
    for (int k = tid; k < nh4; k += blockDim.x) lh4[k] = h4[k];

    // xs levels: lane holds levels lane, +64, +128, +192
    float xsr[4];
#pragma unroll
    for (int k = 0; k < 4; ++k) {
        const int jj = lane + 64 * k;
        xsr[k] = (jj < L) ? mesh[2 * jj + 1] : 2.0f;  // 2.0 never matches
    }
    __syncthreads();

    // local per-chunk stats from staged h (r12-r14-validated path)
    const int ncf = tmax >> 6;
    for (int c = wid; c < ncf; c += nwv) {
        const int i = (c << 6) + lane;
        const float hv = lh[i];
        const float hp = (i > 0) ? lh[i - 1] : 0.0f;
        float mu = (hv > hp) ? hv : -1.0f;
        float md = (hv < hp) ? hv : 2.0f;
        for (int o = 1; o < 64; o <<= 1) {
            mu = fmaxf(mu, __shfl_xor(mu, o));
            md = fminf(md, __shfl_xor(md, o));
        }
        if (lane == 0) { us[c] = mu; dsm[c] = md; }
    }
    __syncthreads();

    if (t >= T) return;

    float u_max = -1.0f, d_min = 2.0f;
    int Acov = 0, Bcov = L;
    int nrec = 0;                 // wave-uniform
    int r_up = 0, r_lo = 0, r_Ap = 0, r_Bp = 0;   // per-lane record slot
    float acc = 0.0f;             // per-lane deferred contributions

    auto flushrec = [&]() {
        if (lane < nrec) {
            float contrib;
            if (r_up) {
                contrib = CT[r_Bp * SPa + r_lo] - CT[r_Bp * SPa + r_Ap];
            } else {
                contrib = -((CT[r_Bp * SPa + L] - CT[r_lo * SPa + L])
                          - (CT[r_Bp * SPa + r_Ap] - CT[r_lo * SPa + r_Ap]));
            }
            acc += contrib;
        }
        nrec = 0;
    };
    auto count_le = [&](float v) -> int {
        return __popcll(__ballot(xsr[0] <= v)) + __popcll(__ballot(xsr[1] <= v))
             + __popcll(__ballot(xsr[2] <= v)) + __popcll(__ballot(xsr[3] <= v));
    };
    auto count_lt = [&](float v) -> int {
        return __popcll(__ballot(xsr[0] < v)) + __popcll(__ballot(xsr[1] < v))
             + __popcll(__ballot(xsr[2] < v)) + __popcll(__ballot(xsr[3] < v));
    };
    auto process_chunk = [&](int c) {
        const int i = (c << 6) + lane;      // i <= ct*64+63 <= tmax
        const float hv = lh[i];
        const float hp = (i > 0) ? lh[i - 1] : 0.0f;
        const bool valid = (i <= t);
        const bool isup = valid && (hv > hp);
        const bool isdn = valid && (hv < hp);
        unsigned long long mup = __ballot(isup && hv > u_max);
        unsigned long long mdn = __ballot(isdn && hv < d_min);
        unsigned long long m = mup | mdn;
        while (m) {
            const int rl = 63 - __builtin_clzll(m);   // largest i first
            const float v = __shfl(hv, rl);
            if ((mup >> rl) & 1ull) {
                u_max = v;
                const int lo = count_le(v);
                if (lo > Acov) {
                    if (lane == nrec) { r_up = 1; r_lo = lo; r_Ap = Acov; r_Bp = Bcov; }
                    ++nrec;
                    Acov = lo;
                    if (nrec == 64) flushrec();
                }
            } else {
                d_min = v;
                const int lo = count_lt(v);
                if (lo < Bcov) {
                    if (lane == nrec) { r_up = 0; r_lo = lo; r_Ap = Acov; r_Bp = Bcov; }
                    ++nrec;
                    Bcov = lo;
                    if (nrec == 64) flushrec();
                }
            }
            const unsigned long long below =
                (rl == 0) ? 0ull : ((1ull << rl) - 1ull);
            mup = __ballot(isup && hv > u_max) & below;
            mdn = __ballot(isdn && hv < d_min) & below;
            m = mup | mdn;
        }
    };

    const int ct = t >> 6;
    process_chunk(ct);  // partial top chunk (valid mask), exact

    for (int g = (ct - 1) >> 6; g >= 0; --g) {   // ct==0 -> skipped
        if (Acov >= L || Bcov <= 0) break;
        const int cbase = g << 6;
        const int c = cbase + lane;
        const bool act = (c < ct);
        const float vu = act ? us[c] : -1.0f;
        const float vd = act ? dsm[c] : 2.0f;
        // suffix scans (higher lanes = later chunks in backward order)
        float su = vu, sd = vd;
        for (int o = 1; o < 64; o <<= 1) {
            su = fmaxf(su, __shfl_down(su, o));
            sd = fminf(sd, __shfl_down(sd, o));
        }
        float sue = __shfl_down(su, 1);
        float sde = __shfl_down(sd, 1);
        if (lane == 63) { sue = -1.0f; sde = 2.0f; }
        const bool enter = act && ((vu > fmaxf(u_max, sue)) ||
                                   (vd < fminf(d_min, sde)));
        unsigned long long em = __ballot(enter);
        while (em) {
            const int rl = 63 - __builtin_clzll(em);
            process_chunk(cbase + rl);
            em &= ~(1ull << rl);
            if (Acov >= L || Bcov <= 0) break;
        }
    }

    flushrec();
    // leftover region keeps initial -1:  C[L][Bcov] - C[Acov][Bcov]
    if (lane == 0) acc -= CT[Bcov * SPa + L] - CT[Bcov * SPa + Acov];
    for (int o = 1; o < 64; o <<= 1) acc += __shfl_xor(acc, o);
    if (lane == 0) out[t] = scale[0] * (acc / (float)n) + offset[0];
}

extern "C" void kernel_launch(void* const* d_in, const int* in_sizes, int n_in,
                              void* d_out, int out_size, void* d_ws, size_t ws_size,
                              hipStream_t stream) {
    const float* h      = (const float*)d_in[0];
    const float* mesh   = (const float*)d_in[1];
    const float* raw    = (const float*)d_in[2];
    const float* scale  = (const float*)d_in[3];
    const float* offset = (const float*)d_in[4];
    float* out = (float*)d_out;

    const int T = in_sizes[0];
    const int n = in_sizes[2];
    const int L = (int)((sqrt(8.0 * (double)n + 1.0) - 1.0) / 2.0 + 0.5);
    const int W = L + 1;
    const int nc = (T + 63) / 64;

    float* CT = (float*)d_ws;                 // W*SPa floats (transposed)

    // K1: direct per-column build -- LDS-resident softplus'd raw prefix,
    // predicated LDS sum loop (no branches / vmcnt stalls), shfl scan.
    const size_t shmem1 = ((size_t)n + 256 + 8 * 256) * sizeof(float); // ~89 KB
    (void)hipFuncSetAttribute(reinterpret_cast<const void*>(build_table_direct),
                              hipFuncAttributeMaxDynamicSharedMemorySize,
                              (int)shmem1);
    hipLaunchKernelGGL(build_table_direct, dim3(W), dim3(512), shmem1, stream,
                       raw, CT, L, n);

    // K2: main, wave per t, h staged + local chunk stats (r14-validated)
    const int nwv = 4;                         // 256 threads = 4 waves
    const int grid = (T + nwv - 1) / nwv;      // 1024 blocks
    const size_t shmem2 = (size_t)(T + 2 * nc) * sizeof(float);  // ~16.9 KB
    hipLaunchKernelGGL(hyst_main, dim3(grid), dim3(256), shmem2, stream,
                       h, mesh, CT, scale, offset, out, T, L, n);
}

// Round 16
// 31.245 us; speedup vs baseline: 11.5034x; 1.4338x over previous
//
#include <hip/hip_runtime.h>
#include <math.h>

// Preisach hysteresis, TWO cheap kernels -- the column scan is eliminated
// entirely. Key identity: every record contribution is
//   C[a2][b] - C[a1][b] = sum_{a1<=j<a2} R[j][b]
// i.e. a CONTIGUOUS segment sum of the row-prefixed table R. So K1 builds
// only R (r9's validated fast row scan, 50 blocks) stored TRANSPOSED
// (RT[b][j], contiguous in j), and K2's deferred lookups become coalesced
// wave-cooperative segment sums (~17 records/wave, ~1 L2 round-trip each).
// Ledger (measured): 1-block build ~60us; redundant build ~34-53us;
// grid.sync ~170us; flag-spin ~400us; r9 3-node best 24.9us.
//
// R[j][b] = sum_{i < min(j+1, b)} softplus(raw[p(i,j)]), j in [0,L), b in [0,L].
// RT[b][j] = R[j][b]; C[a][b] = sum_{j<a} RT[b][j].
// packed p(i,j) = L*i - i*(i-1)/2 + (j-i).

__device__ __forceinline__ float softplus_f(float x) {
    return fmaxf(x, 0.0f) + log1pf(expf(-fabsf(x)));
}

// ---- K1: row prefix scan (r9-validated shape), transposed store ----
__global__ __launch_bounds__(256) void build_rows_T(
    const float* __restrict__ raw,
    float* __restrict__ RT,      // W rows (b in [0,L]) x SPj (j in [0,L))
    int L)
{
    const int SPj = L;
    const int lane = threadIdx.x & 63;
    const int wid  = threadIdx.x >> 6;
    const int j = blockIdx.x * 4 + wid;     // alpha row index
    if (j >= L) return;

    float s[4];
    float run = 0.0f;
#pragma unroll
    for (int q = 0; q < 4; ++q) {
        const int i = 4 * lane + q;          // beta index
        float d = 0.0f;
        if (i <= j) {
            const int p = L * i - (i * (i - 1)) / 2 + (j - i);
            d = softplus_f(raw[p]);
        }
        run += d; s[q] = run;                // lane-local inclusive
    }
    float x = run;                           // lane total
    for (int o = 1; o < 64; o <<= 1) {
        const float tv = __shfl_up(x, o);
        if (lane >= o) x += tv;
    }
    const float excl = x - run;              // exclusive prefix of lanes
#pragma unroll
    for (int q = 0; q < 4; ++q) {
        const int i = 4 * lane + q;
        if (i <= j) RT[(size_t)(i + 1) * SPj + j] = excl + s[q];  // b = i+1
    }
    const float total = __shfl(x, 63);
    for (int b = j + 2 + lane; b <= L; b += 64)
        RT[(size_t)b * SPj + j] = total;
    if (lane == 0) RT[j] = 0.0f;             // b = 0 row
}

// ---- K2: wave-per-t backward-record scan; segment-sum lookups on RT ----
__global__ __launch_bounds__(256) void hyst_main(
    const float* __restrict__ h,
    const float* __restrict__ mesh,
    const float* __restrict__ RTg,
    const float* __restrict__ scale,
    const float* __restrict__ offset,
    float* __restrict__ out,
    int T, int L, int n)
{
    extern __shared__ float sm[];
    const int SPj = L;
    const int nc  = (T + 63) >> 6;

    float* lh  = sm;          // T floats
    float* us  = sm + T;      // nc
    float* dsm = us + nc;     // nc

    const int tid  = threadIdx.x;
    const int lane = tid & 63;
    const int wid  = tid >> 6;
    const int nwv  = blockDim.x >> 6;   // 4

    const int t = blockIdx.x * nwv + wid;

    // stage h[0..tmax] into LDS
    const int tmax = min(T - 1, (int)(blockIdx.x + 1) * nwv - 1);
    const int nh4  = (tmax + 4) >> 2;
    const float4* h4 = (const float4*)h;
    float4* lh4 = (float4*)lh;
    for (int k = tid; k < nh4; k += blockDim.x) lh4[k] = h4[k];

    // xs levels: lane holds levels lane, +64, +128, +192
    float xsr[4];
#pragma unroll
    for (int k = 0; k < 4; ++k) {
        const int jj = lane + 64 * k;
        xsr[k] = (jj < L) ? mesh[2 * jj + 1] : 2.0f;  // 2.0 never matches
    }
    __syncthreads();

    // local per-chunk stats from staged h (r12-r15-validated path)
    const int ncf = tmax >> 6;
    for (int c = wid; c < ncf; c += nwv) {
        const int i = (c << 6) + lane;
        const float hv = lh[i];
        const float hp = (i > 0) ? lh[i - 1] : 0.0f;
        float mu = (hv > hp) ? hv : -1.0f;
        float md = (hv < hp) ? hv : 2.0f;
        for (int o = 1; o < 64; o <<= 1) {
            mu = fmaxf(mu, __shfl_xor(mu, o));
            md = fminf(md, __shfl_xor(md, o));
        }
        if (lane == 0) { us[c] = mu; dsm[c] = md; }
    }
    __syncthreads();

    if (t >= T) return;

    float u_max = -1.0f, d_min = 2.0f;
    int Acov = 0, Bcov = L;
    int nrec = 0;                 // wave-uniform
    int r_up = 0, r_lo = 0, r_Ap = 0, r_Bp = 0;   // per-lane record slot
    float acc = 0.0f;             // per-lane deferred contributions

    // segment-sum lookups: per record r (broadcast via shfl), all 64 lanes
    // cooperatively sum a contiguous run of RT row(s); per-lane partials
    // accumulate into acc (final wave reduce handles them).
    auto flushrec = [&]() {
        for (int r = 0; r < nrec; ++r) {
            const int up = __shfl(r_up, r);
            const int lo = __shfl(r_lo, r);
            const int Ap = __shfl(r_Ap, r);
            const int Bp = __shfl(r_Bp, r);
            if (up) {
                // C[lo][Bp] - C[Ap][Bp] = sum_{Ap<=j<lo} RT[Bp][j]
                float sv = 0.0f;
                for (int j = Ap + lane; j < lo; j += 64)
                    sv += RTg[(size_t)Bp * SPj + j];
                acc += sv;
            } else {
                // -(C[L][Bp]-C[L][lo]-C[Ap][Bp]+C[Ap][lo])
                //   = -sum_{Ap<=j<L} (RT[Bp][j] - RT[lo][j])
                float sv = 0.0f;
                for (int j = Ap + lane; j < L; j += 64)
                    sv += RTg[(size_t)Bp * SPj + j] - RTg[(size_t)lo * SPj + j];
                acc -= sv;
            }
        }
        nrec = 0;
    };
    auto count_le = [&](float v) -> int {
        return __popcll(__ballot(xsr[0] <= v)) + __popcll(__ballot(xsr[1] <= v))
             + __popcll(__ballot(xsr[2] <= v)) + __popcll(__ballot(xsr[3] <= v));
    };
    auto count_lt = [&](float v) -> int {
        return __popcll(__ballot(xsr[0] < v)) + __popcll(__ballot(xsr[1] < v))
             + __popcll(__ballot(xsr[2] < v)) + __popcll(__ballot(xsr[3] < v));
    };
    auto process_chunk = [&](int c) {
        const int i = (c << 6) + lane;      // i <= ct*64+63 <= tmax
        const float hv = lh[i];
        const float hp = (i > 0) ? lh[i - 1] : 0.0f;
        const bool valid = (i <= t);
        const bool isup = valid && (hv > hp);
        const bool isdn = valid && (hv < hp);
        unsigned long long mup = __ballot(isup && hv > u_max);
        unsigned long long mdn = __ballot(isdn && hv < d_min);
        unsigned long long m = mup | mdn;
        while (m) {
            const int rl = 63 - __builtin_clzll(m);   // largest i first
            const float v = __shfl(hv, rl);
            if ((mup >> rl) & 1ull) {
                u_max = v;
                const int lo = count_le(v);
                if (lo > Acov) {
                    if (lane == nrec) { r_up = 1; r_lo = lo; r_Ap = Acov; r_Bp = Bcov; }
                    ++nrec;
                    Acov = lo;
                    if (nrec == 64) flushrec();
                }
            } else {
                d_min = v;
                const int lo = count_lt(v);
                if (lo < Bcov) {
                    if (lane == nrec) { r_up = 0; r_lo = lo; r_Ap = Acov; r_Bp = Bcov; }
                    ++nrec;
                    Bcov = lo;
                    if (nrec == 64) flushrec();
                }
            }
            const unsigned long long below =
                (rl == 0) ? 0ull : ((1ull << rl) - 1ull);
            mup = __ballot(isup && hv > u_max) & below;
            mdn = __ballot(isdn && hv < d_min) & below;
            m = mup | mdn;
        }
    };

    const int ct = t >> 6;
    process_chunk(ct);  // partial top chunk (valid mask), exact

    for (int g = (ct - 1) >> 6; g >= 0; --g) {   // ct==0 -> skipped
        if (Acov >= L || Bcov <= 0) break;
        const int cbase = g << 6;
        const int c = cbase + lane;
        const bool act = (c < ct);
        const float vu = act ? us[c] : -1.0f;
        const float vd = act ? dsm[c] : 2.0f;
        // suffix scans (higher lanes = later chunks in backward order)
        float su = vu, sd = vd;
        for (int o = 1; o < 64; o <<= 1) {
            su = fmaxf(su, __shfl_down(su, o));
            sd = fminf(sd, __shfl_down(sd, o));
        }
        float sue = __shfl_down(su, 1);
        float sde = __shfl_down(sd, 1);
        if (lane == 63) { sue = -1.0f; sde = 2.0f; }
        const bool enter = act && ((vu > fmaxf(u_max, sue)) ||
                                   (vd < fminf(d_min, sde)));
        unsigned long long em = __ballot(enter);
        while (em) {
            const int rl = 63 - __builtin_clzll(em);
            process_chunk(cbase + rl);
            em &= ~(1ull << rl);
            if (Acov >= L || Bcov <= 0) break;
        }
    }

    flushrec();
    // leftover region keeps initial -1:
    //   C[L][Bcov] - C[Acov][Bcov] = sum_{Acov<=j<L} RT[Bcov][j]
    {
        float sv = 0.0f;
        for (int j = Acov + lane; j < L; j += 64)
            sv += RTg[(size_t)Bcov * SPj + j];
        acc -= sv;
    }
    for (int o = 1; o < 64; o <<= 1) acc += __shfl_xor(acc, o);
    if (lane == 0) out[t] = scale[0] * (acc / (float)n) + offset[0];
}

extern "C" void kernel_launch(void* const* d_in, const int* in_sizes, int n_in,
                              void* d_out, int out_size, void* d_ws, size_t ws_size,
                              hipStream_t stream) {
    const float* h      = (const float*)d_in[0];
    const float* mesh   = (const float*)d_in[1];
    const float* raw    = (const float*)d_in[2];
    const float* scale  = (const float*)d_in[3];
    const float* offset = (const float*)d_in[4];
    float* out = (float*)d_out;

    const int T = in_sizes[0];
    const int n = in_sizes[2];
    const int L = (int)((sqrt(8.0 * (double)n + 1.0) - 1.0) / 2.0 + 0.5);
    const int nc = (T + 63) / 64;

    float* RTg = (float*)d_ws;                // (L+1)*L floats (~161 KB)

    // K1: row prefixes, transposed store (50 blocks, wave per row)
    const int nrowblk = (L + 3) / 4;
    hipLaunchKernelGGL(build_rows_T, dim3(nrowblk), dim3(256), 0, stream,
                       raw, RTg, L);

    // K2: main, wave per t, h staged + local chunk stats + segment-sum lookups
    const int nwv = 4;                         // 256 threads = 4 waves
    const int grid = (T + nwv - 1) / nwv;      // 1024 blocks
    const size_t shmem = (size_t)(T + 2 * nc) * sizeof(float);  // ~16.9 KB
    hipLaunchKernelGGL(hyst_main, dim3(grid), dim3(256), shmem, stream,
                       h, mesh, RTg, scale, offset, out, T, L, n);
}

// Round 17
// 28.553 us; speedup vs baseline: 12.5879x; 1.0943x over previous
//
#include <hip/hip_runtime.h>
#include <math.h>

// Preisach hysteresis, TWO cheap kernels; down-record lookups eliminated
// algebraically. The +1 region is exactly the disjoint union of up-record
// rectangles [Ap,lo) x [0,Bp); everything else is -1. Hence
//     m*n = 2*Sum_up - D_total,   D_total = sum_j RT[L][j].
// Down-records only clip Bcov (no memory traffic). Up-record contributions
// are segment sums over DISJOINT j-ranges (total <= L) of single RT rows,
// batched 8-wide so their L2 loads pipeline (r16's serial per-record
// flushrec was the 31.2us regression; r9 best = 24.9us over 3 nodes).
//
// RT[b][j] = R[j][b] = sum_{i<min(j+1,b)} softplus(raw[p(i,j)]).
// C[a][b]-C[a'][b] = sum_{a'<=j<a} RT[b][j].  p(i,j)=L*i-i(i-1)/2+(j-i).

__device__ __forceinline__ float softplus_f(float x) {
    return fmaxf(x, 0.0f) + log1pf(expf(-fabsf(x)));
}

// ---- K1: row prefix scan (r9/r16-validated), transposed store ----
__global__ __launch_bounds__(256) void build_rows_T(
    const float* __restrict__ raw,
    float* __restrict__ RT,      // W rows (b in [0,L]) x SPj (j in [0,L))
    int L)
{
    const int SPj = L;
    const int lane = threadIdx.x & 63;
    const int wid  = threadIdx.x >> 6;
    const int j = blockIdx.x * 4 + wid;     // alpha row index
    if (j >= L) return;

    float s[4];
    float run = 0.0f;
#pragma unroll
    for (int q = 0; q < 4; ++q) {
        const int i = 4 * lane + q;          // beta index
        float d = 0.0f;
        if (i <= j) {
            const int p = L * i - (i * (i - 1)) / 2 + (j - i);
            d = softplus_f(raw[p]);
        }
        run += d; s[q] = run;                // lane-local inclusive
    }
    float x = run;                           // lane total
    for (int o = 1; o < 64; o <<= 1) {
        const float tv = __shfl_up(x, o);
        if (lane >= o) x += tv;
    }
    const float excl = x - run;              // exclusive prefix of lanes
#pragma unroll
    for (int q = 0; q < 4; ++q) {
        const int i = 4 * lane + q;
        if (i <= j) RT[(size_t)(i + 1) * SPj + j] = excl + s[q];  // b = i+1
    }
    const float total = __shfl(x, 63);
    for (int b = j + 2 + lane; b <= L; b += 64)
        RT[(size_t)b * SPj + j] = total;
    if (lane == 0) RT[j] = 0.0f;             // b = 0 row
}

// ---- K2: wave-per-t backward-record scan; up-only batched lookups ----
__global__ __launch_bounds__(256) void hyst_main(
    const float* __restrict__ h,
    const float* __restrict__ mesh,
    const float* __restrict__ RTg,
    const float* __restrict__ scale,
    const float* __restrict__ offset,
    float* __restrict__ out,
    int T, int L, int n)
{
    extern __shared__ float sm[];
    const int SPj = L;
    const int nc  = (T + 63) >> 6;

    float* lh  = sm;          // T floats
    float* us  = sm + T;      // nc
    float* dsm = us + nc;     // nc

    const int tid  = threadIdx.x;
    const int lane = tid & 63;
    const int wid  = tid >> 6;
    const int nwv  = blockDim.x >> 6;   // 4

    const int t = blockIdx.x * nwv + wid;

    // D_total partial: row L of RT = full row sums (4 coalesced loads/lane);
    // issued early so the latency hides under staging / chunk stats.
    float dpart = 0.0f;
    for (int j = lane; j < L; j += 64)
        dpart += RTg[(size_t)L * SPj + j];

    // stage h[0..tmax] into LDS
    const int tmax = min(T - 1, (int)(blockIdx.x + 1) * nwv - 1);
    const int nh4  = (tmax + 4) >> 2;
    const float4* h4 = (const float4*)h;
    float4* lh4 = (float4*)lh;
    for (int k = tid; k < nh4; k += blockDim.x) lh4[k] = h4[k];

    // xs levels: lane holds levels lane, +64, +128, +192
    float xsr[4];
#pragma unroll
    for (int k = 0; k < 4; ++k) {
        const int jj = lane + 64 * k;
        xsr[k] = (jj < L) ? mesh[2 * jj + 1] : 2.0f;  // 2.0 never matches
    }
    __syncthreads();

    // local per-chunk stats from staged h (r12-r16-validated path)
    const int ncf = tmax >> 6;
    for (int c = wid; c < ncf; c += nwv) {
        const int i = (c << 6) + lane;
        const float hv = lh[i];
        const float hp = (i > 0) ? lh[i - 1] : 0.0f;
        float mu = (hv > hp) ? hv : -1.0f;
        float md = (hv < hp) ? hv : 2.0f;
        for (int o = 1; o < 64; o <<= 1) {
            mu = fmaxf(mu, __shfl_xor(mu, o));
            md = fminf(md, __shfl_xor(md, o));
        }
        if (lane == 0) { us[c] = mu; dsm[c] = md; }
    }
    __syncthreads();

    if (t >= T) return;

    float u_max = -1.0f, d_min = 2.0f;
    int Acov = 0, Bcov = L;
    int nrec = 0;                 // wave-uniform count of UP records only
    int r_lo = 0, r_Ap = 0, r_Bp = 0;   // per-lane record slot
    float acc = 0.0f;             // per-lane up-contribution partials

    // batched up-record segment sums: 8 records' loads in flight at once;
    // ranges [Ap,lo) are disjoint, total width <= L, so ~1 load/lane/record.
    auto flushrec = [&]() {
        for (int r0 = 0; r0 < nrec; r0 += 8) {
            float sv = 0.0f;
#pragma unroll
            for (int rr = 0; rr < 8; ++rr) {
                const int r = r0 + rr;
                if (r < nrec) {                       // wave-uniform
                    const int lo = __shfl(r_lo, r);
                    const int Ap = __shfl(r_Ap, r);
                    const int Bp = __shfl(r_Bp, r);
                    for (int j = Ap + lane; j < lo; j += 64)
                        sv += RTg[(size_t)Bp * SPj + j];
                }
            }
            acc += sv;
        }
        nrec = 0;
    };
    auto count_le = [&](float v) -> int {
        return __popcll(__ballot(xsr[0] <= v)) + __popcll(__ballot(xsr[1] <= v))
             + __popcll(__ballot(xsr[2] <= v)) + __popcll(__ballot(xsr[3] <= v));
    };
    auto count_lt = [&](float v) -> int {
        return __popcll(__ballot(xsr[0] < v)) + __popcll(__ballot(xsr[1] < v))
             + __popcll(__ballot(xsr[2] < v)) + __popcll(__ballot(xsr[3] < v));
    };
    auto process_chunk = [&](int c) {
        const int i = (c << 6) + lane;      // i <= ct*64+63 <= tmax
        const float hv = lh[i];
        const float hp = (i > 0) ? lh[i - 1] : 0.0f;
        const bool valid = (i <= t);
        const bool isup = valid && (hv > hp);
        const bool isdn = valid && (hv < hp);
        unsigned long long mup = __ballot(isup && hv > u_max);
        unsigned long long mdn = __ballot(isdn && hv < d_min);
        unsigned long long m = mup | mdn;
        while (m) {
            const int rl = 63 - __builtin_clzll(m);   // largest i first
            const float v = __shfl(hv, rl);
            if ((mup >> rl) & 1ull) {
                u_max = v;
                const int lo = count_le(v);
                if (lo > Acov) {
                    if (lane == nrec) { r_lo = lo; r_Ap = Acov; r_Bp = Bcov; }
                    ++nrec;
                    Acov = lo;
                    if (nrec == 64) flushrec();
                }
            } else {
                d_min = v;
                const int lo = count_lt(v);
                if (lo < Bcov) Bcov = lo;     // clip only -- no lookup needed
            }
            const unsigned long long below =
                (rl == 0) ? 0ull : ((1ull << rl) - 1ull);
            mup = __ballot(isup && hv > u_max) & below;
            mdn = __ballot(isdn && hv < d_min) & below;
            m = mup | mdn;
        }
    };

    const int ct = t >> 6;
    process_chunk(ct);  // partial top chunk (valid mask), exact

    for (int g = (ct - 1) >> 6; g >= 0; --g) {   // ct==0 -> skipped
        if (Acov >= L || Bcov <= 0) break;
        const int cbase = g << 6;
        const int c = cbase + lane;
        const bool act = (c < ct);
        const float vu = act ? us[c] : -1.0f;
        const float vd = act ? dsm[c] : 2.0f;
        // suffix scans (higher lanes = later chunks in backward order)
        float su = vu, sd = vd;
        for (int o = 1; o < 64; o <<= 1) {
            su = fmaxf(su, __shfl_down(su, o));
            sd = fminf(sd, __shfl_down(sd, o));
        }
        float sue = __shfl_down(su, 1);
        float sde = __shfl_down(sd, 1);
        if (lane == 63) { sue = -1.0f; sde = 2.0f; }
        const bool enter = act && ((vu > fmaxf(u_max, sue)) ||
                                   (vd < fminf(d_min, sde)));
        unsigned long long em = __ballot(enter);
        while (em) {
            const int rl = 63 - __builtin_clzll(em);
            process_chunk(cbase + rl);
            em &= ~(1ull << rl);
            if (Acov >= L || Bcov <= 0) break;
        }
    }

    flushrec();
    // m*n = 2*Sum_up - D_total  (downs + leftover are the -1 complement)
    float f = 2.0f * acc - dpart;
    for (int o = 1; o < 64; o <<= 1) f += __shfl_xor(f, o);
    if (lane == 0) out[t] = scale[0] * (f / (float)n) + offset[0];
}

extern "C" void kernel_launch(void* const* d_in, const int* in_sizes, int n_in,
                              void* d_out, int out_size, void* d_ws, size_t ws_size,
                              hipStream_t stream) {
    const float* h      = (const float*)d_in[0];
    const float* mesh   = (const float*)d_in[1];
    const float* raw    = (const float*)d_in[2];
    const float* scale  = (const float*)d_in[3];
    const float* offset = (const float*)d_in[4];
    float* out = (float*)d_out;

    const int T = in_sizes[0];
    const int n = in_sizes[2];
    const int L = (int)((sqrt(8.0 * (double)n + 1.0) - 1.0) / 2.0 + 0.5);
    const int nc = (T + 63) / 64;

    float* RTg = (float*)d_ws;                // (L+1)*L floats (~161 KB)

    // K1: row prefixes, transposed store (50 blocks, wave per row)
    const int nrowblk = (L + 3) / 4;
    hipLaunchKernelGGL(build_rows_T, dim3(nrowblk), dim3(256), 0, stream,
                       raw, RTg, L);

    // K2: main, wave per t; up-only batched segment-sum lookups
    const int nwv = 4;                         // 256 threads = 4 waves
    const int grid = (T + nwv - 1) / nwv;      // 1024 blocks
    const size_t shmem = (size_t)(T + 2 * nc) * sizeof(float);  // ~16.9 KB
    hipLaunchKernelGGL(hyst_main, dim3(grid), dim3(256), shmem, stream,
                       h, mesh, RTg, scale, offset, out, T, L, n);
}